// Round 10
// baseline (394.440 us; speedup 1.0000x reference)
//
#include <hip/hip_runtime.h>
#include <hip/hip_bf16.h>
#include <hip/hip_cooperative_groups.h>
#include <math.h>

namespace cg = cooperative_groups;

#define S_LEN 2048
#define BATCH 2
#define NH 16
#define DK 64
#define DM 1024
#define BS (BATCH * S_LEN)       /* 4096 rows */
#define BHS (BATCH * NH * S_LEN) /* 65536 head-rows */
#define TRP 72                   /* transpose-buffer pitch (shorts): 144B rows keep b128 aligned */
#define PSTR 72

/* fused prep-kernel block ranges */
#define NCONV (3 * BS * DM / 4 / 256) /* 12288 convert blocks */
#define NTRB2 (32 * 32 * 2)           /* 2048 transpose blocks (wv, wo) */
#define NCMP (32 * 32 * 2)            /* 2048 weight-composition blocks (Wq', Wk') */
#define NBC 8                         /* composed-bias blocks */
#define NZRS 16                       /* rowss zero-fill blocks (4096 floats) */
#define NMSK (S_LEN * 64 / 256)       /* 512 maskpack blocks */

using bf16x8  = __attribute__((ext_vector_type(8))) __bf16;
using floatx4 = __attribute__((ext_vector_type(4))) float;
using ushort4v = __attribute__((ext_vector_type(4))) unsigned short;
using uint2v  = __attribute__((ext_vector_type(2))) unsigned int;

__device__ __forceinline__ unsigned short f2bf(float f) {
    union { float f; unsigned u; } v; v.f = f;
    unsigned r = v.u + 0x7fffu + ((v.u >> 16) & 1u);
    return (unsigned short)(r >> 16);
}

// packed RNE f32x2 -> bf16x2 (single VOP3)
__device__ __forceinline__ unsigned cvt_pk_bf16(float a, float b) {
    unsigned r;
    asm("v_cvt_pk_bf16_f32 %0, %1, %2" : "=v"(r) : "v"(a), "v"(b));
    return r;
}

// raw v_exp_f32 (2^x). Inputs bounded (>= -23): no denormal fixup needed.
// Proven -11% on k_attn in round 6 vs OCML wrapper.
__device__ __forceinline__ float exp2_hw(float x) {
    float r;
    asm("v_exp_f32 %0, %1" : "=v"(r) : "v"(x));
    return r;
}
// raw v_rcp_f32 (~1 ulp), replaces the 9-inst IEEE divide sequence.
__device__ __forceinline__ float rcp_hw(float x) {
    float r;
    asm("v_rcp_f32 %0, %1" : "=v"(r) : "v"(x));
    return r;
}

__device__ __forceinline__ float fast_tanh(float x) {
    float e = exp2_hw(x * 2.8853900817779268f);
    return 1.0f - 2.0f * rcp_hw(e + 1.0f);   // e=inf -> 1; e=0 -> -1 (correct limits)
}

// async global->LDS, 16 bytes per lane. LDS dest must be wave-uniform base + lane*16.
__device__ __forceinline__ void gl2lds16(const void* g, void* l) {
    __builtin_amdgcn_global_load_lds(
        (__attribute__((address_space(1))) void*)(uintptr_t)g,
        (__attribute__((address_space(3))) void*)(uintptr_t)l,
        16, 0, 0);
}

// ---------------- fused prep: convert + transposes + weight composition + maskpack ----------------
// (r9) feature transform composed into projection weights:
//   tanh((X@Wq + bq)@wnq + bnq) = tanh(X@(Wq_h@wnq) + (bq_h@wnq + bnq))
// (r10) also zero-fills rowss for the fused out+rmsnorm kernel.
__global__ void k_prep(const float* __restrict__ q, const float* __restrict__ k,
                       const float* __restrict__ v,
                       unsigned short* __restrict__ qb, unsigned short* __restrict__ kb,
                       unsigned short* __restrict__ vb,
                       const float* __restrict__ wq, const float* __restrict__ wk,
                       const float* __restrict__ wv, const float* __restrict__ wo,
                       unsigned short* __restrict__ Wqt, unsigned short* __restrict__ Wkt,
                       unsigned short* __restrict__ Wvt, unsigned short* __restrict__ Wot,
                       const float* __restrict__ wnq, const float* __restrict__ wnk,
                       const float* __restrict__ bq, const float* __restrict__ bk,
                       const float* __restrict__ bnq, const float* __restrict__ bnk,
                       float* __restrict__ bqc, float* __restrict__ bkc,
                       float* __restrict__ rowss,
                       const int* __restrict__ mask, unsigned int* __restrict__ mb) {
    __shared__ unsigned short tile[32][33];
    __shared__ float Ab[32][65];   /* composition A tile, +1 col pad */
    __shared__ float Bb[64][32];   /* composition B tile (broadcast reads) */
    int bid = blockIdx.x;
    if (bid < NCONV) {
        // fp32 -> bf16 convert for Q,K,V
        const int N4 = BS * DM / 4;
        int i = bid * 256 + threadIdx.x;
        int which = i / N4;
        int off = i - which * N4;
        const floatx4* src = (const floatx4*)(which == 0 ? q : which == 1 ? k : v);
        unsigned short* dst = which == 0 ? qb : which == 1 ? kb : vb;
        floatx4 x = src[off];
        ushort4v o;
        unsigned p01 = cvt_pk_bf16(x[0], x[1]);
        unsigned p23 = cvt_pk_bf16(x[2], x[3]);
        o[0] = (unsigned short)p01; o[1] = (unsigned short)(p01 >> 16);
        o[2] = (unsigned short)p23; o[3] = (unsigned short)(p23 >> 16);
        ((ushort4v*)dst)[off] = o;
    } else if (bid < NCONV + NTRB2) {
        // transpose 1024x1024 fp32 -> bf16 [N][K] (wv, wo only)
        int rel = bid - NCONV;
        int z = rel >> 10, xy = rel & 1023, by = xy >> 5, bx = xy & 31;
        const float* src = z == 0 ? wv : wo;
        unsigned short* dst = z == 0 ? Wvt : Wot;
        int tx = threadIdx.x & 31, ty = threadIdx.x >> 5;
#pragma unroll
        for (int i = 0; i < 4; i++) {
            int y = by * 32 + i * 8 + ty;
            tile[i * 8 + ty][tx] = f2bf(src[(size_t)y * DM + bx * 32 + tx]);
        }
        __syncthreads();
#pragma unroll
        for (int i = 0; i < 4; i++) {
            int r = bx * 32 + i * 8 + ty;
            dst[(size_t)r * DM + by * 32 + tx] = tile[tx][i * 8 + ty];
        }
    } else if (bid < NCONV + NTRB2 + NCMP) {
        // composed weight: Wdst^T[o][i] = sum_d Wsrc[i][64h+d] * wn[d][j],  o=64h+j
        int rel = bid - (NCONV + NTRB2);
        int zz = rel >> 10;
        const float* wsrc = zz == 0 ? wq : wk;
        const float* wn = zz == 0 ? wnq : wnk;
        unsigned short* dst = zz == 0 ? Wqt : Wkt;
        int xy = rel & 1023, bo = xy >> 5, bi = xy & 31;
        int o0 = bo * 32, i0 = bi * 32;
        int h = o0 >> 6, j0 = o0 & 63;   /* 32-tile stays within one head */
        int t = threadIdx.x;
        {
            int r = t >> 3, d8 = (t & 7) * 8;
            const float* s = wsrc + (size_t)(i0 + r) * DM + h * 64 + d8;
#pragma unroll
            for (int u = 0; u < 8; u++) Ab[r][d8 + u] = s[u];
            int d = t >> 2, c8 = (t & 3) * 8;
            const float* s2 = wn + d * 64 + j0 + c8;
#pragma unroll
            for (int u = 0; u < 8; u++) Bb[d][c8 + u] = s2[u];
        }
        __syncthreads();
        int il = t & 31, ob = (t >> 5) * 4;
        float s0 = 0.f, s1 = 0.f, s2 = 0.f, s3 = 0.f;
#pragma unroll 8
        for (int d = 0; d < 64; d++) {
            float a = Ab[il][d];
            s0 += a * Bb[d][ob];
            s1 += a * Bb[d][ob + 1];
            s2 += a * Bb[d][ob + 2];
            s3 += a * Bb[d][ob + 3];
        }
        dst[(size_t)(o0 + ob) * DM + i0 + il] = f2bf(s0);
        dst[(size_t)(o0 + ob + 1) * DM + i0 + il] = f2bf(s1);
        dst[(size_t)(o0 + ob + 2) * DM + i0 + il] = f2bf(s2);
        dst[(size_t)(o0 + ob + 3) * DM + i0 + il] = f2bf(s3);
    } else if (bid < NCONV + NTRB2 + NCMP + NBC) {
        // composed bias: b'[64h+j] = sum_d b[64h+d]*wn[d][j] + bn[j]  (fp32)
        int tg = (bid - (NCONV + NTRB2 + NCMP)) * 256 + threadIdx.x;
        int zz = tg >> 10;
        int o = tg & 1023;
        const float* bsrc = zz == 0 ? bq : bk;
        const float* bns = zz == 0 ? bnq : bnk;
        const float* wn = zz == 0 ? wnq : wnk;
        float* dst = zz == 0 ? bqc : bkc;
        int h = o >> 6, j = o & 63;
        float s = bns[j];
        for (int d = 0; d < 64; d++) s += bsrc[h * 64 + d] * wn[d * 64 + j];
        dst[o] = s;
    } else if (bid < NCONV + NTRB2 + NCMP + NBC + NZRS) {
        // zero rowss accumulator for the fused out+rmsnorm
        int t = (bid - (NCONV + NTRB2 + NCMP + NBC)) * 256 + threadIdx.x;
        rowss[t] = 0.0f;
    } else {
        // pack mask int32 -> bitmask
        int t = (bid - (NCONV + NTRB2 + NCMP + NBC + NZRS)) * 256 + threadIdx.x;
        int row = t >> 6, w = t & 63;
        const int* p = mask + (size_t)row * S_LEN + w * 32;
        unsigned bits = 0;
#pragma unroll
        for (int i = 0; i < 32; i++) bits |= (p[i] != 0 ? 1u : 0u) << i;
        mb[t] = bits;
    }
}

// ---------------- merged QKV projection GEMM (composed weights) ----------------
// z==0: qfb row-major = tanh(X@Wq' + bq') * log2e/(8*temp[h]); z==1: kfrag = tanh(X@Wk' + bk')
// z==2: vfrag = X@Wv + bv. grid x = m0 (fast axis): A row-tile L2-resident per XCD.
// NO launch_bounds VGPR cap (r7: (256,4) cost +12us in spills).
__global__ __launch_bounds__(256) void k_gemm_qkv(
    const unsigned short* __restrict__ Qb, const unsigned short* __restrict__ Kb,
    const unsigned short* __restrict__ Vb,
    const unsigned short* __restrict__ Wqt, const unsigned short* __restrict__ Wkt,
    const unsigned short* __restrict__ Wvt,
    const float* __restrict__ bqc, const float* __restrict__ bkc,
    const float* __restrict__ bv,
    const float* __restrict__ temp,
    unsigned short* __restrict__ qfb, unsigned short* __restrict__ kfrag,
    unsigned short* __restrict__ vfrag) {
    const int K = DM;
    int z = blockIdx.z;
    const unsigned short* A  = z == 0 ? Qb  : z == 1 ? Kb  : Vb;
    const unsigned short* Wt = z == 0 ? Wqt : z == 1 ? Wkt : Wvt;
    const float* bias        = z == 0 ? bqc : z == 1 ? bkc : bv;
    int m0 = blockIdx.x * 128, n0 = blockIdx.y * 128;
    __shared__ unsigned short As[128 * 32];
    __shared__ unsigned short Bs[128 * 32];
    __shared__ unsigned short Tr[4][32 * TRP];
    int tid = threadIdx.x;
    int lane = tid & 63, wid = tid >> 6;
    int wy = wid >> 1, wx = wid & 1;
    int l16 = lane & 15, quad = lane >> 4;

    floatx4 acc[4][4] = {};

    for (int kt = 0; kt < K / 32; kt++) {
        int kk = kt * 32;
#pragma unroll
        for (int i = 0; i < 2; i++) {
            int c = i * 256 + tid;
            int row = c >> 2, seg = c & 3;
            gl2lds16(A + (size_t)(m0 + row) * K + kk + seg * 8, &As[c * 8]);
            gl2lds16(Wt + (size_t)(n0 + row) * K + kk + seg * 8, &Bs[c * 8]);
        }
        __syncthreads();
        bf16x8 af[4], bf[4];
#pragma unroll
        for (int mi = 0; mi < 4; mi++)
            af[mi] = *(const bf16x8*)&As[(wy * 64 + mi * 16 + l16) * 32 + quad * 8];
#pragma unroll
        for (int ni = 0; ni < 4; ni++)
            bf[ni] = *(const bf16x8*)&Bs[(wx * 64 + ni * 16 + l16) * 32 + quad * 8];
#pragma unroll
        for (int mi = 0; mi < 4; mi++)
#pragma unroll
            for (int ni = 0; ni < 4; ni++)
                acc[mi][ni] = __builtin_amdgcn_mfma_f32_16x16x32_bf16(af[mi], bf[ni], acc[mi][ni], 0, 0, 0);
        __syncthreads();
    }

    float bvv[4];
#pragma unroll
    for (int ni = 0; ni < 4; ni++) bvv[ni] = bias[n0 + wx * 64 + ni * 16 + l16];
    int head = (n0 + wx * 64) >> 6;
    int mbase = m0 + wy * 64;
    int b = mbase >> 11;
    int bh = b * NH + head;
    unsigned short* tw = &Tr[wid][0];

    if (z == 2) {
        int kt2 = (mbase & (S_LEN - 1)) >> 6;
        size_t tilebase = ((size_t)bh * 32 + kt2) * 4096;
#pragma unroll
        for (int hh = 0; hh < 2; hh++) {
#pragma unroll
            for (int ni2 = 0; ni2 < 2; ni2++) {
                int ni = hh * 2 + ni2;
#pragma unroll
                for (int mi = 0; mi < 4; mi++) {
                    unsigned p01 = cvt_pk_bf16(acc[mi][ni][0] + bvv[ni], acc[mi][ni][1] + bvv[ni]);
                    unsigned p23 = cvt_pk_bf16(acc[mi][ni][2] + bvv[ni], acc[mi][ni][3] + bvv[ni]);
                    int ad = (ni2 * 16 + l16) * TRP + mi * 16 + quad * 4;
                    *(unsigned*)&tw[ad] = p01;
                    *(unsigned*)&tw[ad + 2] = p23;
                }
            }
#pragma unroll
            for (int c = 0; c < 4; c++) {
                int ad = ((c >> 1) * 16 + l16) * TRP + (c & 1) * 32 + quad * 8;
                bf16x8 vv = *(const bf16x8*)&tw[ad];
                *(bf16x8*)&vfrag[tilebase + (size_t)(4 * hh + c) * 512 + lane * 8] = vv;
            }
        }
    } else {
        float sc = z == 0 ? 1.4426950408889634f / (8.0f * temp[head]) : 1.0f;
        size_t rowbase = (size_t)((size_t)bh * S_LEN + (mbase & (S_LEN - 1))) * DK;
        int kt2 = (mbase & (S_LEN - 1)) >> 6;
        size_t tb = ((size_t)bh * 32 + kt2) * 4096;
#pragma unroll
        for (int hh = 0; hh < 2; hh++) {
            // tanh(+composed bias)*sc directly on acc -> Tr [m][d] layout
#pragma unroll
            for (int mi2 = 0; mi2 < 2; mi2++) {
                int mi = hh * 2 + mi2;
#pragma unroll
                for (int ni = 0; ni < 4; ni++) {
                    float t0 = fast_tanh(acc[mi][ni][0] + bvv[ni]) * sc;
                    float t1 = fast_tanh(acc[mi][ni][1] + bvv[ni]) * sc;
                    float t2 = fast_tanh(acc[mi][ni][2] + bvv[ni]) * sc;
                    float t3 = fast_tanh(acc[mi][ni][3] + bvv[ni]) * sc;
                    unsigned p01 = cvt_pk_bf16(t0, t1);
                    unsigned p23 = cvt_pk_bf16(t2, t3);
                    int ad = (mi2 * 16 + quad * 4) * TRP + ni * 16 + l16;
                    tw[ad] = (unsigned short)p01;
                    tw[ad + TRP] = (unsigned short)(p01 >> 16);
                    tw[ad + 2 * TRP] = (unsigned short)p23;
                    tw[ad + 3 * TRP] = (unsigned short)(p23 >> 16);
                }
            }
            // store (wave-private Tr; DS ops wave-ordered)
            if (z == 0) {
#pragma unroll
                for (int c = 0; c < 4; c++) {
                    int g = c * 64 + lane;
                    int ml = g >> 3, dc = g & 7;
                    bf16x8 vv = *(const bf16x8*)&tw[ml * TRP + dc * 8];
                    *(bf16x8*)&qfb[rowbase + (size_t)(hh * 32 + ml) * DK + dc * 8] = vv;
                }
            } else {
#pragma unroll
                for (int c = 0; c < 4; c++) {
                    int ad = ((c >> 1) * 16 + l16) * TRP + (c & 1) * 32 + quad * 8;
                    bf16x8 vv = *(const bf16x8*)&tw[ad];
                    *(bf16x8*)&kfrag[tb + (size_t)(hh * 4 + c) * 512 + lane * 8] = vv;
                }
            }
        }
    }
}

// ---------------- fused out-projection GEMM + RMSNorm (cooperative) ----------------
// r10: acc stays in REGISTERS across grid.sync() -- the 16.7MB fp32 outt
// materialization (write + re-read = 33MB) is gone. Phase 1: GEMM tile, bias
// in-place, per-row sum-of-squares shfl-reduced across l16 lanes, one
// atomicAdd per (row, block) into rowss[4096]. grid.sync(). Phase 2: rsqrt +
// gamma scale from registers, write final output.
// grid (32 m, 16 n) = 512 blocks = 2/CU -- co-residency trivially satisfied.
__global__ __launch_bounds__(256) void k_gemm_out_rms(
    const unsigned short* __restrict__ A, const unsigned short* __restrict__ Wt,
    const float* __restrict__ bias, const float* __restrict__ gamma,
    float* __restrict__ rowss, float* __restrict__ out) {
    const int K = DM;
    int m0 = blockIdx.x * 128, n0 = blockIdx.y * 64;
    __shared__ unsigned short As[128 * 32];
    __shared__ unsigned short Bs[64 * 32];
    int tid = threadIdx.x;
    int lane = tid & 63, wid = tid >> 6;
    int l16 = lane & 15, quad = lane >> 4;

    floatx4 acc[2][4] = {};

    for (int kt = 0; kt < K / 32; kt++) {
        int kk = kt * 32;
#pragma unroll
        for (int i = 0; i < 2; i++) {
            int c = i * 256 + tid;
            gl2lds16(A + (size_t)(m0 + (c >> 2)) * K + kk + (c & 3) * 8, &As[c * 8]);
        }
        gl2lds16(Wt + (size_t)(n0 + (tid >> 2)) * K + kk + (tid & 3) * 8, &Bs[tid * 8]);
        __syncthreads();
        bf16x8 af[2], bf[4];
#pragma unroll
        for (int mi = 0; mi < 2; mi++)
            af[mi] = *(const bf16x8*)&As[(wid * 32 + mi * 16 + l16) * 32 + quad * 8];
#pragma unroll
        for (int ni = 0; ni < 4; ni++)
            bf[ni] = *(const bf16x8*)&Bs[(ni * 16 + l16) * 32 + quad * 8];
#pragma unroll
        for (int mi = 0; mi < 2; mi++)
#pragma unroll
            for (int ni = 0; ni < 4; ni++)
                acc[mi][ni] = __builtin_amdgcn_mfma_f32_16x16x32_bf16(af[mi], bf[ni], acc[mi][ni], 0, 0, 0);
        __syncthreads();
    }

    float bvv[4], g4[4];
#pragma unroll
    for (int ni = 0; ni < 4; ni++) {
        int col = n0 + ni * 16 + l16;
        bvv[ni] = bias[col];
        g4[ni] = gamma[col];
    }
    // phase 1 epilogue: bias in-place + per-row partial sum of squares
#pragma unroll
    for (int mi = 0; mi < 2; mi++) {
#pragma unroll
        for (int r = 0; r < 4; r++) {
            float p = 0.f;
#pragma unroll
            for (int ni = 0; ni < 4; ni++) {
                float v = acc[mi][ni][r] + bvv[ni];
                acc[mi][ni][r] = v;
                p += v * v;
            }
            // reduce across the 16 l16 lanes (same row within a quad)
#pragma unroll
            for (int off = 1; off < 16; off <<= 1) p += __shfl_xor(p, off);
            if (l16 == 0) {
                int row = m0 + wid * 32 + mi * 16 + quad * 4 + r;
                atomicAdd(&rowss[row], p);
            }
        }
    }
    __threadfence();
    cg::this_grid().sync();
    // phase 2: scale from registers, write final output
#pragma unroll
    for (int mi = 0; mi < 2; mi++) {
#pragma unroll
        for (int r = 0; r < 4; r++) {
            int row = m0 + wid * 32 + mi * 16 + quad * 4 + r;
            float rms = rsqrtf(rowss[row] * (1.0f / DM) + 1e-6f);
#pragma unroll
            for (int ni = 0; ni < 4; ni++)
                out[(size_t)row * DM + n0 + ni * 16 + l16] = acc[mi][ni][r] * rms * g4[ni];
        }
    }
}

// ---------------- flash attention, S^T formulation, 16 q-rows per wave ----------------
// Round-6 configuration verbatim -- best measured (70.0 us, reproduced r8/r9).
// Falsified by A/B: barrier-free K (r1, +15us), setprio (r2, null), 2-wave blocks /
// P-swizzle (r4, +3.5us), grouped-MFMA + early P-reads (r7, +23.7us).
// Proven: raw v_exp/v_rcp diet (r6, -9us), bh-major grid / XCD pinning (r0, 5x FETCH).
__global__ __launch_bounds__(256, 4) void k_attn(const unsigned short* __restrict__ qf,
                                                 const unsigned short* __restrict__ kfr,
                                                 const unsigned short* __restrict__ vfr,
                                                 const unsigned long long* __restrict__ mb64,
                                                 unsigned short* __restrict__ ctx) {
    int tid = threadIdx.x, lane = tid & 63, wid = tid >> 6;
    int l16 = lane & 15, quad = lane >> 4;
    int bh = blockIdx.x;
    int b = bh >> 4, h = bh & 15;
    int q0 = blockIdx.y * 64 + wid * 16;

    const unsigned short* qfb = qf + (size_t)bh * S_LEN * DK;
    const unsigned short* kbase = kfr + (size_t)bh * 32 * 4096;
    const unsigned short* vbase = vfr + (size_t)bh * 32 * 4096;

    __shared__ unsigned short Kbuf[2][4096];
    __shared__ unsigned short Plds[4][16 * PSTR];
    unsigned short* myP = Plds[wid];

    union { bf16x8 v; unsigned short u[8]; } one_u;
#pragma unroll
    for (int j = 0; j < 8; j++) one_u.u[j] = 0x3F80;  // bf16 1.0
    bf16x8 ones = one_u.v;

    // Q as B-operand: lane l16 = q-row, k = d
    bf16x8 bq[2];
#pragma unroll
    for (int ks = 0; ks < 2; ks++)
        bq[ks] = *(const bf16x8*)(qfb + (size_t)(q0 + l16) * DK + ks * 32 + quad * 8);

    gl2lds16(kbase + tid * 8, &Kbuf[0][tid * 8]);
    gl2lds16(kbase + 2048 + tid * 8, &Kbuf[0][2048 + tid * 8]);

    floatx4 oacc[4] = {};
    floatx4 lacc = {};
    const unsigned long long* mq = mb64 + (size_t)(q0 + l16) * 32;

    for (int kt = 0; kt < 32; kt++) {
        __syncthreads();   // tile kt staged (issued a full iteration ago); prev reads done
        int nb = (kt + 1) & 1;
        const unsigned short* kn = kbase + (size_t)((kt + 1) & 31) * 4096;
        gl2lds16(kn + tid * 8, &Kbuf[nb][tid * 8]);
        gl2lds16(kn + 2048 + tid * 8, &Kbuf[nb][2048 + tid * 8]);
        // V prefetch (coalesced, consumed after softmax)
        const unsigned short* vt = vbase + (size_t)kt * 4096 + lane * 8;
        bf16x8 vf[8];
#pragma unroll
        for (int i = 0; i < 8; i++) vf[i] = *(const bf16x8*)(vt + i * 512);
        unsigned long long mw = mq[kt];
        const unsigned short* kb = &Kbuf[kt & 1][lane * 8];
        bf16x8 kf8[8];
#pragma unroll
        for (int i = 0; i < 8; i++) kf8[i] = *(const bf16x8*)(kb + i * 512);
        unsigned short* pw = myP + l16 * PSTR;
#pragma unroll
        for (int kbk = 0; kbk < 4; kbk++) {
            floatx4 s = {};
            s = __builtin_amdgcn_mfma_f32_16x16x32_bf16(kf8[kbk * 2], bq[0], s, 0, 0, 0);
            s = __builtin_amdgcn_mfma_f32_16x16x32_bf16(kf8[kbk * 2 + 1], bq[1], s, 0, 0, 0);
            unsigned w = (unsigned)(mw >> (kbk * 16 + quad * 4));
            float p0 = exp2_hw((w & 1u) ? s[0] : -23.0f);
            float p1 = exp2_hw((w & 2u) ? s[1] : -23.0f);
            float p2 = exp2_hw((w & 4u) ? s[2] : -23.0f);
            float p3 = exp2_hw((w & 8u) ? s[3] : -23.0f);
            uint2v pp;
            pp[0] = cvt_pk_bf16(p0, p1);
            pp[1] = cvt_pk_bf16(p2, p3);
            *(uint2v*)&pw[kbk * 16 + quad * 4] = pp;  // one b64 write
        }
        // P A-frags (own rows; DS ops wave-ordered)
        bf16x8 pa0 = *(const bf16x8*)&myP[l16 * PSTR + quad * 8];
        bf16x8 pa1 = *(const bf16x8*)&myP[l16 * PSTR + 32 + quad * 8];
        // row-sum on the MFMA pipe: l = P @ ones
        lacc = __builtin_amdgcn_mfma_f32_16x16x32_bf16(pa0, ones, lacc, 0, 0, 0);
        lacc = __builtin_amdgcn_mfma_f32_16x16x32_bf16(pa1, ones, lacc, 0, 0, 0);
#pragma unroll
        for (int ni = 0; ni < 4; ni++) {
            oacc[ni] = __builtin_amdgcn_mfma_f32_16x16x32_bf16(pa0, vf[ni * 2], oacc[ni], 0, 0, 0);
            oacc[ni] = __builtin_amdgcn_mfma_f32_16x16x32_bf16(pa1, vf[ni * 2 + 1], oacc[ni], 0, 0, 0);
        }
    }
    // epilogue: lacc rows align with oacc rows (q = quad*4+r) -> no cross-lane work
    float inv[4];
#pragma unroll
    for (int r = 0; r < 4; r++) inv[r] = rcp_hw(lacc[r]);
#pragma unroll
    for (int ni = 0; ni < 4; ni++) {
        int d = ni * 16 + l16;
#pragma unroll
        for (int r = 0; r < 4; r++) {
            int s = q0 + quad * 4 + r;
            ctx[(size_t)(b * S_LEN + s) * DM + h * DK + d] = f2bf(oacc[ni][r] * inv[r]);
        }
    }
}

extern "C" void kernel_launch(void* const* d_in, const int* in_sizes, int n_in,
                              void* d_out, int out_size, void* d_ws, size_t ws_size,
                              hipStream_t stream) {
    const float* Q = (const float*)d_in[0];
    const float* K = (const float*)d_in[1];
    const float* V = (const float*)d_in[2];
    const int* mask = (const int*)d_in[3];
    const float* wq = (const float*)d_in[4];
    const float* bq = (const float*)d_in[5];
    const float* wk = (const float*)d_in[6];
    const float* bk = (const float*)d_in[7];
    const float* wv = (const float*)d_in[8];
    const float* bv = (const float*)d_in[9];
    const float* wo = (const float*)d_in[10];
    const float* bo = (const float*)d_in[11];
    const float* wnq = (const float*)d_in[12];
    const float* bnq = (const float*)d_in[13];
    const float* wnk = (const float*)d_in[14];
    const float* bnk = (const float*)d_in[15];
    const float* temp = (const float*)d_in[16];
    const float* gamma = (const float*)d_in[17];

    char* w = (char*)d_ws;
    size_t o = 0;
    auto alloc = [&](size_t bytes) {
        char* p = w + o;
        o += (bytes + 255) & ~(size_t)255;
        return p;
    };
    unsigned short* Qb = (unsigned short*)alloc((size_t)BS * DM * 2);
    unsigned short* Kb = (unsigned short*)alloc((size_t)BS * DM * 2);
    unsigned short* Vb = (unsigned short*)alloc((size_t)BS * DM * 2);
    unsigned short* Wqt = (unsigned short*)alloc((size_t)DM * DM * 2);  /* composed */
    unsigned short* Wkt = (unsigned short*)alloc((size_t)DM * DM * 2);  /* composed */
    unsigned short* Wvt = (unsigned short*)alloc((size_t)DM * DM * 2);
    unsigned short* Wot = (unsigned short*)alloc((size_t)DM * DM * 2);
    float* bqc = (float*)alloc((size_t)DM * 4);
    float* bkc = (float*)alloc((size_t)DM * 4);
    float* rowss = (float*)alloc((size_t)BS * 4);
    unsigned short* vfrag = (unsigned short*)alloc((size_t)BHS * DK * 2);
    unsigned short* qfb = (unsigned short*)alloc((size_t)BHS * DK * 2);
    unsigned short* kfrag = (unsigned short*)alloc((size_t)BHS * DK * 2);
    unsigned int* mb = (unsigned int*)alloc((size_t)S_LEN * (S_LEN / 32) * 4);
    unsigned short* ctx = (unsigned short*)alloc((size_t)BS * DM * 2);

    k_prep<<<dim3(NCONV + NTRB2 + NCMP + NBC + NZRS + NMSK), 256, 0, stream>>>(
        Q, K, V, Qb, Kb, Vb, wq, wk, wv, wo, Wqt, Wkt, Wvt, Wot,
        wnq, wnk, bq, bk, bnq, bnk, bqc, bkc, rowss, mask, mb);

    k_gemm_qkv<<<dim3(32, 8, 3), 256, 0, stream>>>(Qb, Kb, Vb, Wqt, Wkt, Wvt,
                                                   bqc, bkc, bv, temp,
                                                   qfb, kfrag, vfrag);

    k_attn<<<dim3(BATCH * NH, S_LEN / 64), 256, 0, stream>>>(
        qfb, kfrag, vfrag, (const unsigned long long*)mb, ctx);

    {
        const unsigned short* Ap = ctx;
        const unsigned short* Wp = Wot;
        const float* bp = bo;
        const float* gp = gamma;
        float* rp = rowss;
        float* op = (float*)d_out;
        void* kargs[] = {(void*)&Ap, (void*)&Wp, (void*)&bp, (void*)&gp,
                         (void*)&rp, (void*)&op};
        hipLaunchCooperativeKernel((const void*)k_gemm_out_rms, dim3(32, 16),
                                   dim3(256), kargs, 0, stream);
    }
}

// Round 12
// 273.965 us; speedup vs baseline: 1.4397x; 1.4397x over previous
//
#include <hip/hip_runtime.h>
#include <hip/hip_bf16.h>
#include <math.h>

#define S_LEN 2048
#define BATCH 2
#define NH 16
#define DK 64
#define DM 1024
#define BS (BATCH * S_LEN)       /* 4096 rows */
#define BHS (BATCH * NH * S_LEN) /* 65536 head-rows */
#define TRP 72                   /* transpose-buffer pitch (shorts): 144B rows keep b128 aligned */
#define PSTR 72

/* fused prep-kernel block ranges */
#define NCONV (3 * BS * DM / 4 / 256) /* 12288 convert blocks */
#define NTRB2 (32 * 32 * 2)           /* 2048 transpose blocks (wv, wo) */
#define NCMP (32 * 32 * 2)            /* 2048 weight-composition blocks (Wq', Wk') */
#define NBC 8                         /* composed-bias blocks */
#define NZRS 16                       /* rowss zero-fill blocks (4096 floats) */
#define NMSK (S_LEN * 64 / 256)       /* 512 maskpack blocks */

using bf16x8  = __attribute__((ext_vector_type(8))) __bf16;
using floatx4 = __attribute__((ext_vector_type(4))) float;
using ushort4v = __attribute__((ext_vector_type(4))) unsigned short;
using uint2v  = __attribute__((ext_vector_type(2))) unsigned int;

__device__ __forceinline__ unsigned short f2bf(float f) {
    union { float f; unsigned u; } v; v.f = f;
    unsigned r = v.u + 0x7fffu + ((v.u >> 16) & 1u);
    return (unsigned short)(r >> 16);
}

__device__ __forceinline__ float bf2f(unsigned short b) {
    union { unsigned u; float f; } v; v.u = (unsigned)b << 16;
    return v.f;
}

// packed RNE f32x2 -> bf16x2 (single VOP3)
__device__ __forceinline__ unsigned cvt_pk_bf16(float a, float b) {
    unsigned r;
    asm("v_cvt_pk_bf16_f32 %0, %1, %2" : "=v"(r) : "v"(a), "v"(b));
    return r;
}

// raw v_exp_f32 (2^x). Inputs bounded (>= -23): no denormal fixup needed.
// Proven -11% on k_attn in round 6 vs OCML wrapper.
__device__ __forceinline__ float exp2_hw(float x) {
    float r;
    asm("v_exp_f32 %0, %1" : "=v"(r) : "v"(x));
    return r;
}
// raw v_rcp_f32 (~1 ulp), replaces the 9-inst IEEE divide sequence.
__device__ __forceinline__ float rcp_hw(float x) {
    float r;
    asm("v_rcp_f32 %0, %1" : "=v"(r) : "v"(x));
    return r;
}

__device__ __forceinline__ float fast_tanh(float x) {
    float e = exp2_hw(x * 2.8853900817779268f);
    return 1.0f - 2.0f * rcp_hw(e + 1.0f);   // e=inf -> 1; e=0 -> -1 (correct limits)
}

// async global->LDS, 16 bytes per lane. LDS dest must be wave-uniform base + lane*16.
__device__ __forceinline__ void gl2lds16(const void* g, void* l) {
    __builtin_amdgcn_global_load_lds(
        (__attribute__((address_space(1))) void*)(uintptr_t)g,
        (__attribute__((address_space(3))) void*)(uintptr_t)l,
        16, 0, 0);
}

// ---------------- fused prep: convert + transposes + weight composition + maskpack ----------------
// (r9) feature transform composed into projection weights:
//   tanh((X@Wq + bq)@wnq + bnq) = tanh(X@(Wq_h@wnq) + (bq_h@wnq + bnq))
// Also zero-fills rowss (per-row sum-of-squares accumulator for the out-path).
__global__ void k_prep(const float* __restrict__ q, const float* __restrict__ k,
                       const float* __restrict__ v,
                       unsigned short* __restrict__ qb, unsigned short* __restrict__ kb,
                       unsigned short* __restrict__ vb,
                       const float* __restrict__ wq, const float* __restrict__ wk,
                       const float* __restrict__ wv, const float* __restrict__ wo,
                       unsigned short* __restrict__ Wqt, unsigned short* __restrict__ Wkt,
                       unsigned short* __restrict__ Wvt, unsigned short* __restrict__ Wot,
                       const float* __restrict__ wnq, const float* __restrict__ wnk,
                       const float* __restrict__ bq, const float* __restrict__ bk,
                       const float* __restrict__ bnq, const float* __restrict__ bnk,
                       float* __restrict__ bqc, float* __restrict__ bkc,
                       float* __restrict__ rowss,
                       const int* __restrict__ mask, unsigned int* __restrict__ mb) {
    __shared__ unsigned short tile[32][33];
    __shared__ float Ab[32][65];   /* composition A tile, +1 col pad */
    __shared__ float Bb[64][32];   /* composition B tile (broadcast reads) */
    int bid = blockIdx.x;
    if (bid < NCONV) {
        // fp32 -> bf16 convert for Q,K,V
        const int N4 = BS * DM / 4;
        int i = bid * 256 + threadIdx.x;
        int which = i / N4;
        int off = i - which * N4;
        const floatx4* src = (const floatx4*)(which == 0 ? q : which == 1 ? k : v);
        unsigned short* dst = which == 0 ? qb : which == 1 ? kb : vb;
        floatx4 x = src[off];
        ushort4v o;
        unsigned p01 = cvt_pk_bf16(x[0], x[1]);
        unsigned p23 = cvt_pk_bf16(x[2], x[3]);
        o[0] = (unsigned short)p01; o[1] = (unsigned short)(p01 >> 16);
        o[2] = (unsigned short)p23; o[3] = (unsigned short)(p23 >> 16);
        ((ushort4v*)dst)[off] = o;
    } else if (bid < NCONV + NTRB2) {
        // transpose 1024x1024 fp32 -> bf16 [N][K] (wv, wo only)
        int rel = bid - NCONV;
        int z = rel >> 10, xy = rel & 1023, by = xy >> 5, bx = xy & 31;
        const float* src = z == 0 ? wv : wo;
        unsigned short* dst = z == 0 ? Wvt : Wot;
        int tx = threadIdx.x & 31, ty = threadIdx.x >> 5;
#pragma unroll
        for (int i = 0; i < 4; i++) {
            int y = by * 32 + i * 8 + ty;
            tile[i * 8 + ty][tx] = f2bf(src[(size_t)y * DM + bx * 32 + tx]);
        }
        __syncthreads();
#pragma unroll
        for (int i = 0; i < 4; i++) {
            int r = bx * 32 + i * 8 + ty;
            dst[(size_t)r * DM + by * 32 + tx] = tile[tx][i * 8 + ty];
        }
    } else if (bid < NCONV + NTRB2 + NCMP) {
        // composed weight: Wdst^T[o][i] = sum_d Wsrc[i][64h+d] * wn[d][j],  o=64h+j
        int rel = bid - (NCONV + NTRB2);
        int zz = rel >> 10;
        const float* wsrc = zz == 0 ? wq : wk;
        const float* wn = zz == 0 ? wnq : wnk;
        unsigned short* dst = zz == 0 ? Wqt : Wkt;
        int xy = rel & 1023, bo = xy >> 5, bi = xy & 31;
        int o0 = bo * 32, i0 = bi * 32;
        int h = o0 >> 6, j0 = o0 & 63;   /* 32-tile stays within one head */
        int t = threadIdx.x;
        {
            int r = t >> 3, d8 = (t & 7) * 8;
            const float* s = wsrc + (size_t)(i0 + r) * DM + h * 64 + d8;
#pragma unroll
            for (int u = 0; u < 8; u++) Ab[r][d8 + u] = s[u];
            int d = t >> 2, c8 = (t & 3) * 8;
            const float* s2 = wn + d * 64 + j0 + c8;
#pragma unroll
            for (int u = 0; u < 8; u++) Bb[d][c8 + u] = s2[u];
        }
        __syncthreads();
        int il = t & 31, ob = (t >> 5) * 4;
        float s0 = 0.f, s1 = 0.f, s2 = 0.f, s3 = 0.f;
#pragma unroll 8
        for (int d = 0; d < 64; d++) {
            float a = Ab[il][d];
            s0 += a * Bb[d][ob];
            s1 += a * Bb[d][ob + 1];
            s2 += a * Bb[d][ob + 2];
            s3 += a * Bb[d][ob + 3];
        }
        dst[(size_t)(o0 + ob) * DM + i0 + il] = f2bf(s0);
        dst[(size_t)(o0 + ob + 1) * DM + i0 + il] = f2bf(s1);
        dst[(size_t)(o0 + ob + 2) * DM + i0 + il] = f2bf(s2);
        dst[(size_t)(o0 + ob + 3) * DM + i0 + il] = f2bf(s3);
    } else if (bid < NCONV + NTRB2 + NCMP + NBC) {
        // composed bias: b'[64h+j] = sum_d b[64h+d]*wn[d][j] + bn[j]  (fp32)
        int tg = (bid - (NCONV + NTRB2 + NCMP)) * 256 + threadIdx.x;
        int zz = tg >> 10;
        int o = tg & 1023;
        const float* bsrc = zz == 0 ? bq : bk;
        const float* bns = zz == 0 ? bnq : bnk;
        const float* wn = zz == 0 ? wnq : wnk;
        float* dst = zz == 0 ? bqc : bkc;
        int h = o >> 6, j = o & 63;
        float s = bns[j];
        for (int d = 0; d < 64; d++) s += bsrc[h * 64 + d] * wn[d * 64 + j];
        dst[o] = s;
    } else if (bid < NCONV + NTRB2 + NCMP + NBC + NZRS) {
        // zero rowss accumulator
        int t = (bid - (NCONV + NTRB2 + NCMP + NBC)) * 256 + threadIdx.x;
        rowss[t] = 0.0f;
    } else {
        // pack mask int32 -> bitmask
        int t = (bid - (NCONV + NTRB2 + NCMP + NBC + NZRS)) * 256 + threadIdx.x;
        int row = t >> 6, w = t & 63;
        const int* p = mask + (size_t)row * S_LEN + w * 32;
        unsigned bits = 0;
#pragma unroll
        for (int i = 0; i < 32; i++) bits |= (p[i] != 0 ? 1u : 0u) << i;
        mb[t] = bits;
    }
}

// ---------------- merged QKV projection GEMM (composed weights) ----------------
// z==0: qfb row-major = tanh(X@Wq' + bq') * log2e/(8*temp[h]); z==1: kfrag = tanh(X@Wk' + bk')
// z==2: vfrag = X@Wv + bv. grid x = m0 (fast axis): A row-tile L2-resident per XCD.
// NO launch_bounds VGPR cap (r7: (256,4) cost +12us in spills).
__global__ __launch_bounds__(256) void k_gemm_qkv(
    const unsigned short* __restrict__ Qb, const unsigned short* __restrict__ Kb,
    const unsigned short* __restrict__ Vb,
    const unsigned short* __restrict__ Wqt, const unsigned short* __restrict__ Wkt,
    const unsigned short* __restrict__ Wvt,
    const float* __restrict__ bqc, const float* __restrict__ bkc,
    const float* __restrict__ bv,
    const float* __restrict__ temp,
    unsigned short* __restrict__ qfb, unsigned short* __restrict__ kfrag,
    unsigned short* __restrict__ vfrag) {
    const int K = DM;
    int z = blockIdx.z;
    const unsigned short* A  = z == 0 ? Qb  : z == 1 ? Kb  : Vb;
    const unsigned short* Wt = z == 0 ? Wqt : z == 1 ? Wkt : Wvt;
    const float* bias        = z == 0 ? bqc : z == 1 ? bkc : bv;
    int m0 = blockIdx.x * 128, n0 = blockIdx.y * 128;
    __shared__ unsigned short As[128 * 32];
    __shared__ unsigned short Bs[128 * 32];
    __shared__ unsigned short Tr[4][32 * TRP];
    int tid = threadIdx.x;
    int lane = tid & 63, wid = tid >> 6;
    int wy = wid >> 1, wx = wid & 1;
    int l16 = lane & 15, quad = lane >> 4;

    floatx4 acc[4][4] = {};

    for (int kt = 0; kt < K / 32; kt++) {
        int kk = kt * 32;
#pragma unroll
        for (int i = 0; i < 2; i++) {
            int c = i * 256 + tid;
            int row = c >> 2, seg = c & 3;
            gl2lds16(A + (size_t)(m0 + row) * K + kk + seg * 8, &As[c * 8]);
            gl2lds16(Wt + (size_t)(n0 + row) * K + kk + seg * 8, &Bs[c * 8]);
        }
        __syncthreads();
        bf16x8 af[4], bf[4];
#pragma unroll
        for (int mi = 0; mi < 4; mi++)
            af[mi] = *(const bf16x8*)&As[(wy * 64 + mi * 16 + l16) * 32 + quad * 8];
#pragma unroll
        for (int ni = 0; ni < 4; ni++)
            bf[ni] = *(const bf16x8*)&Bs[(wx * 64 + ni * 16 + l16) * 32 + quad * 8];
#pragma unroll
        for (int mi = 0; mi < 4; mi++)
#pragma unroll
            for (int ni = 0; ni < 4; ni++)
                acc[mi][ni] = __builtin_amdgcn_mfma_f32_16x16x32_bf16(af[mi], bf[ni], acc[mi][ni], 0, 0, 0);
        __syncthreads();
    }

    float bvv[4];
#pragma unroll
    for (int ni = 0; ni < 4; ni++) bvv[ni] = bias[n0 + wx * 64 + ni * 16 + l16];
    int head = (n0 + wx * 64) >> 6;
    int mbase = m0 + wy * 64;
    int b = mbase >> 11;
    int bh = b * NH + head;
    unsigned short* tw = &Tr[wid][0];

    if (z == 2) {
        int kt2 = (mbase & (S_LEN - 1)) >> 6;
        size_t tilebase = ((size_t)bh * 32 + kt2) * 4096;
#pragma unroll
        for (int hh = 0; hh < 2; hh++) {
#pragma unroll
            for (int ni2 = 0; ni2 < 2; ni2++) {
                int ni = hh * 2 + ni2;
#pragma unroll
                for (int mi = 0; mi < 4; mi++) {
                    unsigned p01 = cvt_pk_bf16(acc[mi][ni][0] + bvv[ni], acc[mi][ni][1] + bvv[ni]);
                    unsigned p23 = cvt_pk_bf16(acc[mi][ni][2] + bvv[ni], acc[mi][ni][3] + bvv[ni]);
                    int ad = (ni2 * 16 + l16) * TRP + mi * 16 + quad * 4;
                    *(unsigned*)&tw[ad] = p01;
                    *(unsigned*)&tw[ad + 2] = p23;
                }
            }
#pragma unroll
            for (int c = 0; c < 4; c++) {
                int ad = ((c >> 1) * 16 + l16) * TRP + (c & 1) * 32 + quad * 8;
                bf16x8 vv = *(const bf16x8*)&tw[ad];
                *(bf16x8*)&vfrag[tilebase + (size_t)(4 * hh + c) * 512 + lane * 8] = vv;
            }
        }
    } else {
        float sc = z == 0 ? 1.4426950408889634f / (8.0f * temp[head]) : 1.0f;
        size_t rowbase = (size_t)((size_t)bh * S_LEN + (mbase & (S_LEN - 1))) * DK;
        int kt2 = (mbase & (S_LEN - 1)) >> 6;
        size_t tb = ((size_t)bh * 32 + kt2) * 4096;
#pragma unroll
        for (int hh = 0; hh < 2; hh++) {
            // tanh(+composed bias)*sc directly on acc -> Tr [m][d] layout
#pragma unroll
            for (int mi2 = 0; mi2 < 2; mi2++) {
                int mi = hh * 2 + mi2;
#pragma unroll
                for (int ni = 0; ni < 4; ni++) {
                    float t0 = fast_tanh(acc[mi][ni][0] + bvv[ni]) * sc;
                    float t1 = fast_tanh(acc[mi][ni][1] + bvv[ni]) * sc;
                    float t2 = fast_tanh(acc[mi][ni][2] + bvv[ni]) * sc;
                    float t3 = fast_tanh(acc[mi][ni][3] + bvv[ni]) * sc;
                    unsigned p01 = cvt_pk_bf16(t0, t1);
                    unsigned p23 = cvt_pk_bf16(t2, t3);
                    int ad = (mi2 * 16 + quad * 4) * TRP + ni * 16 + l16;
                    tw[ad] = (unsigned short)p01;
                    tw[ad + TRP] = (unsigned short)(p01 >> 16);
                    tw[ad + 2 * TRP] = (unsigned short)p23;
                    tw[ad + 3 * TRP] = (unsigned short)(p23 >> 16);
                }
            }
            // store (wave-private Tr; DS ops wave-ordered)
            if (z == 0) {
#pragma unroll
                for (int c = 0; c < 4; c++) {
                    int g = c * 64 + lane;
                    int ml = g >> 3, dc = g & 7;
                    bf16x8 vv = *(const bf16x8*)&tw[ml * TRP + dc * 8];
                    *(bf16x8*)&qfb[rowbase + (size_t)(hh * 32 + ml) * DK + dc * 8] = vv;
                }
            } else {
#pragma unroll
                for (int c = 0; c < 4; c++) {
                    int ad = ((c >> 1) * 16 + l16) * TRP + (c & 1) * 32 + quad * 8;
                    bf16x8 vv = *(const bf16x8*)&tw[ad];
                    *(bf16x8*)&kfrag[tb + (size_t)(hh * 4 + c) * 512 + lane * 8] = vv;
                }
            }
        }
    }
}

// ---------------- out-projection GEMM: bf16 intermediate + rowss atomics ----------------
// r12 (= r11 intent, rmsnorm index bug fixed): launch boundary stays as the grid
// barrier (r10's cooperative grid.sync spun ~90us across 8 XCDs -- falsified).
// Write outt as bf16 (halves intermediate traffic) + atomicAdd per-row
// sum-of-squares partials (fp32 acc) into rowss; k_rmsnorm is a pure scale pass.
__global__ __launch_bounds__(256) void k_gemm_out(const unsigned short* __restrict__ A,
                                                  const unsigned short* __restrict__ Wt,
                                                  const float* __restrict__ bias,
                                                  unsigned short* __restrict__ out_bf,
                                                  float* __restrict__ rowss) {
    const int K = DM;
    int m0 = blockIdx.x * 128, n0 = blockIdx.y * 64;
    __shared__ unsigned short As[128 * 32];
    __shared__ unsigned short Bs[64 * 32];
    int tid = threadIdx.x;
    int lane = tid & 63, wid = tid >> 6;
    int l16 = lane & 15, quad = lane >> 4;

    floatx4 acc[2][4] = {};

    for (int kt = 0; kt < K / 32; kt++) {
        int kk = kt * 32;
#pragma unroll
        for (int i = 0; i < 2; i++) {
            int c = i * 256 + tid;
            gl2lds16(A + (size_t)(m0 + (c >> 2)) * K + kk + (c & 3) * 8, &As[c * 8]);
        }
        gl2lds16(Wt + (size_t)(n0 + (tid >> 2)) * K + kk + (tid & 3) * 8, &Bs[tid * 8]);
        __syncthreads();
        bf16x8 af[2], bf[4];
#pragma unroll
        for (int mi = 0; mi < 2; mi++)
            af[mi] = *(const bf16x8*)&As[(wid * 32 + mi * 16 + l16) * 32 + quad * 8];
#pragma unroll
        for (int ni = 0; ni < 4; ni++)
            bf[ni] = *(const bf16x8*)&Bs[(ni * 16 + l16) * 32 + quad * 8];
#pragma unroll
        for (int mi = 0; mi < 2; mi++)
#pragma unroll
            for (int ni = 0; ni < 4; ni++)
                acc[mi][ni] = __builtin_amdgcn_mfma_f32_16x16x32_bf16(af[mi], bf[ni], acc[mi][ni], 0, 0, 0);
        __syncthreads();
    }

    float bvv[4];
#pragma unroll
    for (int ni = 0; ni < 4; ni++) bvv[ni] = bias[n0 + ni * 16 + l16];
#pragma unroll
    for (int mi = 0; mi < 2; mi++) {
#pragma unroll
        for (int r = 0; r < 4; r++) {
            int row = m0 + wid * 32 + mi * 16 + quad * 4 + r;
            float p = 0.f;
#pragma unroll
            for (int ni = 0; ni < 4; ni++) {
                float v = acc[mi][ni][r] + bvv[ni];
                p += v * v;
                out_bf[(size_t)row * DM + n0 + ni * 16 + l16] = f2bf(v);
            }
            // reduce partial across the 16 l16 lanes (same row within a quad;
            // xor offsets 1,2,4,8 stay inside the 16-lane group)
#pragma unroll
            for (int off = 1; off < 16; off <<= 1) p += __shfl_xor(p, off);
            if (l16 == 0) atomicAdd(&rowss[row], p);
        }
    }
}

// ---------------- RMSNorm: pure scale pass (sums precomputed in rowss) ----------------
// 256 threads x 4 bf16/thread = 1024 = DM exactly (r11's crash was 8/thread = 2x OOB).
__global__ __launch_bounds__(256) void k_rmsnorm(const unsigned short* __restrict__ x,
                                                 const float* __restrict__ rowss,
                                                 const float* __restrict__ gamma,
                                                 float* __restrict__ out) {
    int row = blockIdx.x, tid = threadIdx.x;
    float rms = rsqrtf(rowss[row] * (1.0f / DM) + 1e-6f);
    ushort4v a = *(const ushort4v*)(x + (size_t)row * DM + tid * 4);  /* 4 bf16, b64 load */
    floatx4 g = ((const floatx4*)gamma)[tid];
    floatx4 o;
#pragma unroll
    for (int j = 0; j < 4; j++) o[j] = bf2f(a[j]) * rms * g[j];
    ((floatx4*)(out + (size_t)row * DM))[tid] = o;
}

// ---------------- flash attention, S^T formulation, 16 q-rows per wave ----------------
// Round-6 configuration verbatim -- best measured (70.0 us, reproduced r8/r9).
// Falsified by A/B: barrier-free K (r1), setprio (r2), 2-wave blocks/P-swizzle (r4),
// grouped-MFMA + early P-reads (r7), cooperative grid.sync fusion (r10, ~90us spin).
// Proven: raw v_exp/v_rcp diet (r6), bh-major grid / XCD pinning (r0).
__global__ __launch_bounds__(256, 4) void k_attn(const unsigned short* __restrict__ qf,
                                                 const unsigned short* __restrict__ kfr,
                                                 const unsigned short* __restrict__ vfr,
                                                 const unsigned long long* __restrict__ mb64,
                                                 unsigned short* __restrict__ ctx) {
    int tid = threadIdx.x, lane = tid & 63, wid = tid >> 6;
    int l16 = lane & 15, quad = lane >> 4;
    int bh = blockIdx.x;
    int b = bh >> 4, h = bh & 15;
    int q0 = blockIdx.y * 64 + wid * 16;

    const unsigned short* qfb = qf + (size_t)bh * S_LEN * DK;
    const unsigned short* kbase = kfr + (size_t)bh * 32 * 4096;
    const unsigned short* vbase = vfr + (size_t)bh * 32 * 4096;

    __shared__ unsigned short Kbuf[2][4096];
    __shared__ unsigned short Plds[4][16 * PSTR];
    unsigned short* myP = Plds[wid];

    union { bf16x8 v; unsigned short u[8]; } one_u;
#pragma unroll
    for (int j = 0; j < 8; j++) one_u.u[j] = 0x3F80;  // bf16 1.0
    bf16x8 ones = one_u.v;

    // Q as B-operand: lane l16 = q-row, k = d
    bf16x8 bq[2];
#pragma unroll
    for (int ks = 0; ks < 2; ks++)
        bq[ks] = *(const bf16x8*)(qfb + (size_t)(q0 + l16) * DK + ks * 32 + quad * 8);

    gl2lds16(kbase + tid * 8, &Kbuf[0][tid * 8]);
    gl2lds16(kbase + 2048 + tid * 8, &Kbuf[0][2048 + tid * 8]);

    floatx4 oacc[4] = {};
    floatx4 lacc = {};
    const unsigned long long* mq = mb64 + (size_t)(q0 + l16) * 32;

    for (int kt = 0; kt < 32; kt++) {
        __syncthreads();   // tile kt staged (issued a full iteration ago); prev reads done
        int nb = (kt + 1) & 1;
        const unsigned short* kn = kbase + (size_t)((kt + 1) & 31) * 4096;
        gl2lds16(kn + tid * 8, &Kbuf[nb][tid * 8]);
        gl2lds16(kn + 2048 + tid * 8, &Kbuf[nb][2048 + tid * 8]);
        // V prefetch (coalesced, consumed after softmax)
        const unsigned short* vt = vbase + (size_t)kt * 4096 + lane * 8;
        bf16x8 vf[8];
#pragma unroll
        for (int i = 0; i < 8; i++) vf[i] = *(const bf16x8*)(vt + i * 512);
        unsigned long long mw = mq[kt];
        const unsigned short* kb = &Kbuf[kt & 1][lane * 8];
        bf16x8 kf8[8];
#pragma unroll
        for (int i = 0; i < 8; i++) kf8[i] = *(const bf16x8*)(kb + i * 512);
        unsigned short* pw = myP + l16 * PSTR;
#pragma unroll
        for (int kbk = 0; kbk < 4; kbk++) {
            floatx4 s = {};
            s = __builtin_amdgcn_mfma_f32_16x16x32_bf16(kf8[kbk * 2], bq[0], s, 0, 0, 0);
            s = __builtin_amdgcn_mfma_f32_16x16x32_bf16(kf8[kbk * 2 + 1], bq[1], s, 0, 0, 0);
            unsigned w = (unsigned)(mw >> (kbk * 16 + quad * 4));
            float p0 = exp2_hw((w & 1u) ? s[0] : -23.0f);
            float p1 = exp2_hw((w & 2u) ? s[1] : -23.0f);
            float p2 = exp2_hw((w & 4u) ? s[2] : -23.0f);
            float p3 = exp2_hw((w & 8u) ? s[3] : -23.0f);
            uint2v pp;
            pp[0] = cvt_pk_bf16(p0, p1);
            pp[1] = cvt_pk_bf16(p2, p3);
            *(uint2v*)&pw[kbk * 16 + quad * 4] = pp;  // one b64 write
        }
        // P A-frags (own rows; DS ops wave-ordered)
        bf16x8 pa0 = *(const bf16x8*)&myP[l16 * PSTR + quad * 8];
        bf16x8 pa1 = *(const bf16x8*)&myP[l16 * PSTR + 32 + quad * 8];
        // row-sum on the MFMA pipe: l = P @ ones
        lacc = __builtin_amdgcn_mfma_f32_16x16x32_bf16(pa0, ones, lacc, 0, 0, 0);
        lacc = __builtin_amdgcn_mfma_f32_16x16x32_bf16(pa1, ones, lacc, 0, 0, 0);
#pragma unroll
        for (int ni = 0; ni < 4; ni++) {
            oacc[ni] = __builtin_amdgcn_mfma_f32_16x16x32_bf16(pa0, vf[ni * 2], oacc[ni], 0, 0, 0);
            oacc[ni] = __builtin_amdgcn_mfma_f32_16x16x32_bf16(pa1, vf[ni * 2 + 1], oacc[ni], 0, 0, 0);
        }
    }
    // epilogue: lacc rows align with oacc rows (q = quad*4+r) -> no cross-lane work
    float inv[4];
#pragma unroll
    for (int r = 0; r < 4; r++) inv[r] = rcp_hw(lacc[r]);
#pragma unroll
    for (int ni = 0; ni < 4; ni++) {
        int d = ni * 16 + l16;
#pragma unroll
        for (int r = 0; r < 4; r++) {
            int s = q0 + quad * 4 + r;
            ctx[(size_t)(b * S_LEN + s) * DM + h * DK + d] = f2bf(oacc[ni][r] * inv[r]);
        }
    }
}

extern "C" void kernel_launch(void* const* d_in, const int* in_sizes, int n_in,
                              void* d_out, int out_size, void* d_ws, size_t ws_size,
                              hipStream_t stream) {
    const float* Q = (const float*)d_in[0];
    const float* K = (const float*)d_in[1];
    const float* V = (const float*)d_in[2];
    const int* mask = (const int*)d_in[3];
    const float* wq = (const float*)d_in[4];
    const float* bq = (const float*)d_in[5];
    const float* wk = (const float*)d_in[6];
    const float* bk = (const float*)d_in[7];
    const float* wv = (const float*)d_in[8];
    const float* bv = (const float*)d_in[9];
    const float* wo = (const float*)d_in[10];
    const float* bo = (const float*)d_in[11];
    const float* wnq = (const float*)d_in[12];
    const float* bnq = (const float*)d_in[13];
    const float* wnk = (const float*)d_in[14];
    const float* bnk = (const float*)d_in[15];
    const float* temp = (const float*)d_in[16];
    const float* gamma = (const float*)d_in[17];

    char* w = (char*)d_ws;
    size_t o = 0;
    auto alloc = [&](size_t bytes) {
        char* p = w + o;
        o += (bytes + 255) & ~(size_t)255;
        return p;
    };
    unsigned short* Qb = (unsigned short*)alloc((size_t)BS * DM * 2);
    unsigned short* Kb = (unsigned short*)alloc((size_t)BS * DM * 2);
    unsigned short* Vb = (unsigned short*)alloc((size_t)BS * DM * 2);
    unsigned short* Wqt = (unsigned short*)alloc((size_t)DM * DM * 2);  /* composed */
    unsigned short* Wkt = (unsigned short*)alloc((size_t)DM * DM * 2);  /* composed */
    unsigned short* Wvt = (unsigned short*)alloc((size_t)DM * DM * 2);
    unsigned short* Wot = (unsigned short*)alloc((size_t)DM * DM * 2);
    float* bqc = (float*)alloc((size_t)DM * 4);
    float* bkc = (float*)alloc((size_t)DM * 4);
    float* rowss = (float*)alloc((size_t)BS * 4);
    unsigned short* vfrag = (unsigned short*)alloc((size_t)BHS * DK * 2);
    unsigned short* qfb = (unsigned short*)alloc((size_t)BHS * DK * 2);
    unsigned short* kfrag = (unsigned short*)alloc((size_t)BHS * DK * 2);
    unsigned int* mb = (unsigned int*)alloc((size_t)S_LEN * (S_LEN / 32) * 4);
    unsigned short* ctx = (unsigned short*)alloc((size_t)BS * DM * 2);
    unsigned short* outb = (unsigned short*)alloc((size_t)BS * DM * 2);

    k_prep<<<dim3(NCONV + NTRB2 + NCMP + NBC + NZRS + NMSK), 256, 0, stream>>>(
        Q, K, V, Qb, Kb, Vb, wq, wk, wv, wo, Wqt, Wkt, Wvt, Wot,
        wnq, wnk, bq, bk, bnq, bnk, bqc, bkc, rowss, mask, mb);

    k_gemm_qkv<<<dim3(32, 8, 3), 256, 0, stream>>>(Qb, Kb, Vb, Wqt, Wkt, Wvt,
                                                   bqc, bkc, bv, temp,
                                                   qfb, kfrag, vfrag);

    k_attn<<<dim3(BATCH * NH, S_LEN / 64), 256, 0, stream>>>(
        qfb, kfrag, vfrag, (const unsigned long long*)mb, ctx);

    k_gemm_out<<<dim3(32, 16), 256, 0, stream>>>(ctx, Wot, bo, outb, rowss);
    k_rmsnorm<<<dim3(BS), 256, 0, stream>>>(outb, rowss, gamma, (float*)d_out);
}